// Round 1
// 146.210 us; speedup vs baseline: 1.0731x; 1.0731x over previous
//
#include <hip/hip_runtime.h>
#include <hip/hip_bf16.h>
#include <math.h>

#define N_ROWS 4096
#define DIM    512
#define M_ROWS 8192
#define BK     32
#define NTILES 64            // 8192 / 128
#define NBLOCKS 2080         // 64*65/2 triangular tiles
// exp(sim/0.1) = exp2(sim * 10*log2(e))
#define EXP_SCALE 14.4269504088896340736f

typedef unsigned short ushort_t;
typedef __attribute__((ext_vector_type(8))) short short8;
typedef __attribute__((ext_vector_type(4))) float f32x4;

// float -> bf16 bits, round-to-nearest-even (inputs are finite)
__device__ __forceinline__ ushort_t f2bf(float x) {
  unsigned int bits = __float_as_uint(x);
  unsigned int lsb = (bits >> 16) & 1u;
  bits += 0x7fffu + lsb;
  return (ushort_t)(bits >> 16);
}

__device__ __forceinline__ void store4bf(ushort_t* p, float4 v, float s) {
  union { ushort_t u[4]; uint2 d; } pk;
  pk.u[0] = f2bf(v.x * s);
  pk.u[1] = f2bf(v.y * s);
  pk.u[2] = f2bf(v.z * s);
  pk.u[3] = f2bf(v.w * s);
  *(uint2*)p = pk.d;
}

// async global -> LDS, 16 bytes per lane (lds dest = wave-uniform base + lane*16)
__device__ __forceinline__ void async16(const ushort_t* g, ushort_t* l) {
  __builtin_amdgcn_global_load_lds(
      (const __attribute__((address_space(1))) void*)g,
      (__attribute__((address_space(3))) void*)l,
      16, 0, 0);
}

// ---------------------------------------------------------------------------
// Kernel 1: per-row L2 normalize (fp32 math), emit bf16 reps[8192][512] and
// exact fp32 positives pos[i] = dot(z_i, z_j). One wave per row-pair.
// Also zeroes denom[] (replaces a separate hipMemsetAsync dispatch).
// ---------------------------------------------------------------------------
__global__ __launch_bounds__(64) void norm_kernel(
    const float* __restrict__ ei, const float* __restrict__ ej,
    ushort_t* __restrict__ reps, float* __restrict__ pos,
    float* __restrict__ denom) {
  int b = blockIdx.x;
  int lane = threadIdx.x;  // 0..63
  if (lane == 0) {
    denom[b] = 0.0f;
    denom[b + N_ROWS] = 0.0f;
  }
  const float4* pi = (const float4*)(ei + (size_t)b * DIM);
  const float4* pj = (const float4*)(ej + (size_t)b * DIM);
  float4 a0 = pi[lane];
  float4 a1 = pi[lane + 64];
  float4 b0 = pj[lane];
  float4 b1 = pj[lane + 64];

  float si = a0.x*a0.x + a0.y*a0.y + a0.z*a0.z + a0.w*a0.w
           + a1.x*a1.x + a1.y*a1.y + a1.z*a1.z + a1.w*a1.w;
  float sj = b0.x*b0.x + b0.y*b0.y + b0.z*b0.z + b0.w*b0.w
           + b1.x*b1.x + b1.y*b1.y + b1.z*b1.z + b1.w*b1.w;
  float dp = a0.x*b0.x + a0.y*b0.y + a0.z*b0.z + a0.w*b0.w
           + a1.x*b1.x + a1.y*b1.y + a1.z*b1.z + a1.w*b1.w;

#pragma unroll
  for (int m = 32; m >= 1; m >>= 1) {
    si += __shfl_xor(si, m, 64);
    sj += __shfl_xor(sj, m, 64);
    dp += __shfl_xor(dp, m, 64);
  }
  float ii = 1.0f / fmaxf(sqrtf(si), 1e-12f);
  float ij = 1.0f / fmaxf(sqrtf(sj), 1e-12f);
  if (lane == 0) pos[b] = dp * ii * ij;

  ushort_t* ri = reps + (size_t)b * DIM;
  ushort_t* rj = reps + (size_t)(b + N_ROWS) * DIM;
  store4bf(ri + lane * 4,       a0, ii);
  store4bf(ri + 256 + lane * 4, a1, ii);
  store4bf(rj + lane * 4,       b0, ij);
  store4bf(rj + 256 + lane * 4, b1, ij);
}

// ---------------------------------------------------------------------------
// Kernel 2: fused sim-GEMM + exp + masked row/col reduction.
// 128x128 tile per block (4 waves, 4x4 of 16x16x32 bf16 MFMA each).
// Changes vs previous version:
//  - linear triangular grid (2080 blocks, no early-exit waste) + bijective
//    XCD swizzle (2080 % 8 == 0) for per-XCD L2 panel locality
//  - 2-phase double-buffered LDS: stage tile t+1 before computing tile t,
//    ONE __syncthreads per K-step (its vmcnt(0)+lgkmcnt(0) drain is the
//    pipeline wait) -> global->LDS latency hidden under MFMA
//  - LDS XOR swizzle (16B granule, slot ^= (row>>1)&3) applied on BOTH sides:
//    pre-swizzled global source (global_load_lds dest stays linear) and
//    swizzled ds_read_b128 address. Kills the 8-way bank conflict
//    (lanes of a quad all hit the same 16B slot with 64B rows).
// ---------------------------------------------------------------------------
__global__ __launch_bounds__(256) void sim_kernel(
    const ushort_t* __restrict__ reps, float* __restrict__ denom) {
  // --- triangular block index, XCD-swizzled (2080 = 8 * 260) ---
  int id = blockIdx.x;
  id = (id & 7) * (NBLOCKS / 8) + (id >> 3);
  int bj = (int)((sqrtf(8.0f * (float)id + 1.0f) - 1.0f) * 0.5f);
  while ((bj + 1) * (bj + 2) / 2 <= id) ++bj;
  while (bj * (bj + 1) / 2 > id) --bj;
  int bi = id - bj * (bj + 1) / 2;   // 0 <= bi <= bj < 64

  __shared__ ushort_t As[2][128 * BK];
  __shared__ ushort_t Bs[2][128 * BK];

  int tid  = threadIdx.x;
  int wave = tid >> 6, lane = tid & 63;
  int wr = wave >> 1, wc = wave & 1;
  int quad = lane >> 4, l15 = lane & 15;

  // staging: chunk c covers LDS bytes [c*1024, c*1024+1024) = tile rows c*16..c*16+15
  // source element chunk is XOR-swizzled by row so the linear LDS dest ends up
  // holding row r's k-slot s data at slot (s ^ ((r>>1)&3)).
  int c0 = wave * 2, c1 = c0 + 1;
  int srow  = lane >> 2;                               // row within chunk, 0..15
  int selem = ((lane & 3) ^ ((srow >> 1) & 3)) * 8;    // swizzled k-element offset
  const ushort_t* gA0 = reps + (size_t)(bi * 128 + c0 * 16 + srow) * DIM + selem;
  const ushort_t* gA1 = reps + (size_t)(bi * 128 + c1 * 16 + srow) * DIM + selem;
  const ushort_t* gB0 = reps + (size_t)(bj * 128 + c0 * 16 + srow) * DIM + selem;
  const ushort_t* gB1 = reps + (size_t)(bj * 128 + c1 * 16 + srow) * DIM + selem;

  f32x4 zero4 = {0.0f, 0.0f, 0.0f, 0.0f};
  f32x4 acc[4][4];
#pragma unroll
  for (int tr = 0; tr < 4; ++tr)
#pragma unroll
    for (int tc = 0; tc < 4; ++tc) acc[tr][tc] = zero4;

  // swizzled k-slot for fragment reads: row r = (multiple of 16) + l15,
  // so (r>>1)&3 == (l15>>1)&3 (uniform across tr/wr).
  int sqr = (quad ^ ((l15 >> 1) & 3)) * 8;

  // --- prologue: stage k-tile 0 into buffer 0 ---
  async16(gA0, &As[0][c0 * 512]);
  async16(gA1, &As[0][c1 * 512]);
  async16(gB0, &Bs[0][c0 * 512]);
  async16(gB1, &Bs[0][c1 * 512]);
  __syncthreads();  // vmcnt(0) drain: tile 0 visible

  int cur = 0;
  for (int kk = 0; kk < DIM; kk += BK) {
    int nxt = cur ^ 1;
    // prefetch next k-tile into the other buffer; its latency is hidden
    // under this iteration's ds_read+MFMA and drained by the syncthreads below
    if (kk + BK < DIM) {
      async16(gA0 + kk + BK, &As[nxt][c0 * 512]);
      async16(gA1 + kk + BK, &As[nxt][c1 * 512]);
      async16(gB0 + kk + BK, &Bs[nxt][c0 * 512]);
      async16(gB1 + kk + BK, &Bs[nxt][c1 * 512]);
    }

    short8 aF[4], bF[4];
#pragma unroll
    for (int t = 0; t < 4; ++t) {
      aF[t] = *(const short8*)(&As[cur][(wr * 64 + t * 16 + l15) * BK + sqr]);
      bF[t] = *(const short8*)(&Bs[cur][(wc * 64 + t * 16 + l15) * BK + sqr]);
    }
#pragma unroll
    for (int tr = 0; tr < 4; ++tr)
#pragma unroll
      for (int tc = 0; tc < 4; ++tc)
        acc[tr][tc] = __builtin_amdgcn_mfma_f32_16x16x32_bf16(
            aF[tr], bF[tc], acc[tr][tc], 0, 0, 0);

    __syncthreads();  // ds_reads of buf[cur] done by all waves; prefetch drained
    cur = nxt;
  }

  // epilogue: e = exp(sim/T), mask diagonal, row sums + (off-diag) col sums.
  // C layout: col = l15 (+ tc*16), row = quad*4 + r (+ tr*16)  [m89/m91]
  int rowg_base = bi * 128 + wr * 64;
  int colg_base = bj * 128 + wc * 64;

  f32x4 rsum[4];
  float csum[4] = {0.0f, 0.0f, 0.0f, 0.0f};
#pragma unroll
  for (int tr = 0; tr < 4; ++tr) rsum[tr] = zero4;

#pragma unroll
  for (int tr = 0; tr < 4; ++tr) {
    int rowg0 = rowg_base + tr * 16 + quad * 4;
#pragma unroll
    for (int tc = 0; tc < 4; ++tc) {
      int colg = colg_base + tc * 16 + l15;
      f32x4 a = acc[tr][tc];
      f32x4 e;
#pragma unroll
      for (int r = 0; r < 4; ++r) {
        float v = exp2f(a[r] * EXP_SCALE);
        e[r] = ((rowg0 + r) == colg) ? 0.0f : v;
      }
      rsum[tr] += e;
      csum[tc] += e[0] + e[1] + e[2] + e[3];
    }
  }

  // reduce row sums across the 16 lanes sharing `quad` (masks 1,2,4,8)
#pragma unroll
  for (int m = 1; m <= 8; m <<= 1)
#pragma unroll
    for (int tr = 0; tr < 4; ++tr)
#pragma unroll
      for (int r = 0; r < 4; ++r)
        rsum[tr][r] += __shfl_xor(rsum[tr][r], m, 64);

  if (l15 == 0) {
#pragma unroll
    for (int tr = 0; tr < 4; ++tr)
#pragma unroll
      for (int r = 0; r < 4; ++r)
        atomicAdd(&denom[rowg_base + tr * 16 + quad * 4 + r], rsum[tr][r]);
  }

  if (bi != bj) {
    // reduce col sums across quads (masks 16,32)
#pragma unroll
    for (int m = 16; m <= 32; m <<= 1)
#pragma unroll
      for (int tc = 0; tc < 4; ++tc)
        csum[tc] += __shfl_xor(csum[tc], m, 64);
    if (quad == 0) {
#pragma unroll
      for (int tc = 0; tc < 4; ++tc)
        atomicAdd(&denom[colg_base + tc * 16 + l15], csum[tc]);
    }
  }
}

// ---------------------------------------------------------------------------
// Kernel 3: loss = mean over rows of [log(denom) - pos/T]
// ---------------------------------------------------------------------------
__global__ __launch_bounds__(256) void loss_kernel(
    const float* __restrict__ denom, const float* __restrict__ pos,
    float* __restrict__ out) {
  __shared__ float red[4];
  int tid = threadIdx.x;
  float p = 0.0f;
  for (int r = tid; r < M_ROWS; r += 256)
    p += logf(denom[r]) - pos[r & (N_ROWS - 1)] * 10.0f;
#pragma unroll
  for (int m = 32; m >= 1; m >>= 1) p += __shfl_xor(p, m, 64);
  if ((tid & 63) == 0) red[tid >> 6] = p;
  __syncthreads();
  if (tid == 0)
    out[0] = (red[0] + red[1] + red[2] + red[3]) * (1.0f / M_ROWS);
}

extern "C" void kernel_launch(void* const* d_in, const int* in_sizes, int n_in,
                              void* d_out, int out_size, void* d_ws, size_t ws_size,
                              hipStream_t stream) {
  const float* ei = (const float*)d_in[0];
  const float* ej = (const float*)d_in[1];
  float* out = (float*)d_out;

  char* ws = (char*)d_ws;
  ushort_t* reps = (ushort_t*)ws;                                   // 8 MB bf16
  float* denom = (float*)(ws + (size_t)M_ROWS * DIM * 2);           // 32 KB
  float* pos = (float*)(ws + (size_t)M_ROWS * DIM * 2 + M_ROWS * 4);// 16 KB

  norm_kernel<<<N_ROWS, 64, 0, stream>>>(ei, ej, reps, pos, denom);
  sim_kernel<<<NBLOCKS, 256, 0, stream>>>(reps, denom);
  loss_kernel<<<1, 256, 0, stream>>>(denom, pos, out);
}